// Round 21
// baseline (379.024 us; speedup 1.0000x reference)
//
#include <hip/hip_runtime.h>
#include <hip/hip_fp16.h>

#define NNODES 100000
#define NEDGES 3200000
#define NGRAPH 1000
#define NPG    100
#define MDIM   32
#define NCDIM  10

#define CAP     48         // bucket capacity; P(deg>48)~1.8e-3/node -> ~200 ovf edges
#define OVF_CAP 4096

#define NPART   8          // scatter partitions (== XCD count)
#define PSIZE   12500      // nodes per partition
#define FCHUNK  6250       // edges per chunk
#define FBLKS   (NEDGES / FCHUNK)   // 512 chunks

// ws layout (float units), total 36.0 MB (ws >= 40.4 MB proven in r12):
#define W_S2    0           // slot2: 100000*48 + 64 pad ints
#define W_CNT   4800064     // 100000 ints
#define W_DINV  4900064     // 100000 floats
#define W_XD4   5000064     // 100000 float4 (16B aligned)
#define W_A4    5400064     // 100000 float4
#define W_G1H   5800064     // 3200000 uints ([node][32] half2)
#define W_OVF   9000064     // 1 + 2*4096 ints
#define WS_FLOATS 9008257   // 36.0 MB

// ---------------- K1: bucket fill, XCD-partitioned; builds cnt on the fly ---------
__global__ __launch_bounds__(256) void k_fillbkt(const int* __restrict__ ei,
                                                 int* __restrict__ cnt,
                                                 int* __restrict__ slot2,
                                                 int* __restrict__ ovf) {
    int part  = blockIdx.x & (NPART - 1);
    int chunk = blockIdx.x >> 3;
    int base  = chunk * FCHUNK;
    int end   = base + FCHUNK;
    int clo   = part * PSIZE;
    int chi   = clo + PSIZE;
    for (int e = base + threadIdx.x; e < end; e += 256) {
        int c = ei[NEDGES + e];
        if (c >= clo && c < chi) {
            int r = ei[e];
            int idx = atomicAdd(&cnt[c], 1);
            if (idx < CAP) {
                slot2[c * CAP + idx] = r;
            } else {
                int o = atomicAdd(&ovf[0], 1);
                if (o < OVF_CAP) { ovf[1 + 2 * o] = r; ovf[2 + 2 * o] = c; }
            }
        }
    }
}

// ---------------- K2: dinv + packed xd4 from final cnt ----------------
__global__ __launch_bounds__(256) void k_prep(const int* __restrict__ cnt,
                                              const float* __restrict__ x,
                                              float* __restrict__ dinv,
                                              float4* __restrict__ xd4) {
    int i = blockIdx.x * blockDim.x + threadIdx.x;
    if (i >= NNODES) return;
    float di = rsqrtf((float)cnt[i] + 1.0f);
    dinv[i] = di;
    xd4[i] = make_float4(x[3 * i], x[3 * i + 1], x[3 * i + 2], di);
}

// ---------------- K3: a4[i] + g1h row fused (g1h = fp16 dinv*relu(a.W1+b1)) -------
__global__ __launch_bounds__(256) void k_ag1(const int* __restrict__ cnt,
                                             const int* __restrict__ slot2,
                                             const float4* __restrict__ xd4,
                                             float4* __restrict__ a4,
                                             const float* __restrict__ W1,
                                             const float* __restrict__ b1,
                                             uint4* __restrict__ g1h4) {
    int i = blockIdx.x * blockDim.x + threadIdx.x;
    if (i >= NNODES) return;
    int d = min(cnt[i], CAP);
    int s = i * CAP;
    int d8 = d & ~7;
    float ax = 0.f, ay = 0.f, az = 0.f;
    for (int k = 0; k < d8; k += 8) {            // mask-free main
        float4 xr[8];
        #pragma unroll
        for (int j = 0; j < 8; ++j) xr[j] = xd4[slot2[s + k + j]];
        #pragma unroll
        for (int j = 0; j < 8; ++j) {
            ax += xr[j].w * xr[j].x; ay += xr[j].w * xr[j].y; az += xr[j].w * xr[j].z;
        }
    }
    if (d8 < d) {                                // clamped tail (<8 edges)
        float4 xr[8];
        #pragma unroll
        for (int j = 0; j < 8; ++j) {
            int idx = slot2[s + d8 + j];         // in-row, may be garbage past d
            xr[j] = xd4[(d8 + j < d) ? idx : 0];
        }
        #pragma unroll
        for (int j = 0; j < 8; ++j) {
            float u = (d8 + j < d) ? xr[j].w : 0.f;
            ax += u * xr[j].x; ay += u * xr[j].y; az += u * xr[j].z;
        }
    }
    float4 xi = xd4[i];
    float di = xi.w;
    float a0 = di * (ax + di * xi.x);
    float a1 = di * (ay + di * xi.y);
    float a2 = di * (az + di * xi.z);
    a4[i] = make_float4(a0, a1, a2, di);
    // fused g1h row: 8 chunks of 8 features (4 half2 words) each
    #pragma unroll
    for (int ch = 0; ch < 8; ++ch) {
        uint4 wv;
        unsigned int* wp = (unsigned int*)&wv;
        #pragma unroll
        for (int q = 0; q < 4; ++q) {
            int f0 = ch * 8 + 2 * q;             // wave-uniform -> s_load W1/b1
            float h0 = fmaxf(a0 * W1[f0]     + a1 * W1[64 + f0]     + a2 * W1[128 + f0]     + b1[f0], 0.f);
            float h1 = fmaxf(a0 * W1[f0 + 1] + a1 * W1[64 + f0 + 1] + a2 * W1[128 + f0 + 1] + b1[f0 + 1], 0.f);
            __half2 hv = __floats2half2_rn(di * h0, di * h1);
            wp[q] = *(unsigned int*)&hv;
        }
        g1h4[i * 8 + ch] = wv;
    }
}

// ---------------- K3b: exact fixup of a4 for overflow edges (tiny) ----------------
__global__ void k_ovfA(const int* __restrict__ ovf, const float4* __restrict__ xd4,
                       const float* __restrict__ dinv, float* __restrict__ a4f) {
    int n = min(ovf[0], OVF_CAP);
    for (int k = threadIdx.x; k < n; k += 256) {
        int r = ovf[1 + 2 * k];
        int c = ovf[2 + 2 * k];
        float4 xr = xd4[r];
        float s = dinv[c] * xr.w;
        atomicAdd(&a4f[c * 4 + 0], s * xr.x);
        atomicAdd(&a4f[c * 4 + 1], s * xr.y);
        atomicAdd(&a4f[c * 4 + 2], s * xr.z);
    }
}

// ---------------- K3c: recompute g1h rows of overflow targets (idempotent) --------
__global__ void k_ovfG(const int* __restrict__ ovf, const float4* __restrict__ a4,
                       const float* __restrict__ W1, const float* __restrict__ b1,
                       unsigned int* __restrict__ g1h) {
    int n = min(ovf[0], OVF_CAP);
    for (int idx = threadIdx.x; idx < n * 32; idx += 256) {
        int k = idx >> 5, j = idx & 31;
        int c = ovf[2 + 2 * k];
        float4 ai = a4[c];
        int f0 = 2 * j, f1 = f0 + 1;
        float h0 = fmaxf(ai.x * W1[f0] + ai.y * W1[64 + f0] + ai.z * W1[128 + f0] + b1[f0], 0.f);
        float h1 = fmaxf(ai.x * W1[f1] + ai.y * W1[64 + f1] + ai.z * W1[128 + f1] + b1[f1], 0.f);
        __half2 hv = __floats2half2_rn(ai.w * h0, ai.w * h1);
        g1h[c * 32 + j] = *(unsigned int*)&hv;
    }
}

// ---------------- K5: per-graph, 8 waves (512 thr); r18 structure -----------------
__global__ __launch_bounds__(512, 8) void k_fusedA(
    const int* __restrict__ cnt, const int* __restrict__ slot2,
    const int* __restrict__ ovf,
    const unsigned int* __restrict__ g1h, const float* __restrict__ dinv,
    const float* __restrict__ mv,
    const float* __restrict__ W2, const float* __restrict__ b2,
    const float* __restrict__ Wc1, const float* __restrict__ bc1,
    const float* __restrict__ Wc2, const float* __restrict__ bc2,
    float* __restrict__ out)
{
    __shared__ float aggh[NPG * 66];   // 26.4 KB, even pad -> aligned float2 rows
    __shared__ float pools[8 * 128];   // 4 KB
    __shared__ float zbuf[160];
    __shared__ float zz[64];

    int g = blockIdx.x;
    int t = threadIdx.x;
    int wb = t >> 6;           // wave 0..7
    int lane = t & 63;
    int h = lane >> 5;         // which edge of the pair this half-wave handles
    int j = lane & 31;         // feature-pair index (features 2j, 2j+1)
    // waves 0-3 own 13 contiguous rows, waves 4-7 own 12:  4*13 + 4*12 = 100
    int nn    = (wb < 4) ? 13 : 12;
    int rbase = (wb < 4) ? wb * 13 : 52 + (wb - 4) * 12;

    // ---- phase 1: per-node aggregation; 256B wave-load covers TWO edges ----
    for (int i = 0; i < nn; ++i) {
        int n = rbase + i;
        int node = g * NPG + n;
        int s = node * CAP;
        int d = min(cnt[node], CAP);
        int d16 = d & ~15;
        float acc0 = 0.f, acc1 = 0.f;
        for (int k0 = 0; k0 < d16; k0 += 16) {        // mask-free main loop
            int rr[8];
            #pragma unroll
            for (int jj = 0; jj < 8; ++jj)
                rr[jj] = slot2[s + k0 + 2 * jj + h];  // all positions valid
            unsigned int pre[8];
            #pragma unroll
            for (int jj = 0; jj < 8; ++jj)
                pre[jj] = g1h[rr[jj] * 32 + j];       // coalesced 256B/wave
            #pragma unroll
            for (int jj = 0; jj < 8; ++jj) {
                float2 f = __half22float2(*(__half2*)&pre[jj]);
                acc0 += f.x;
                acc1 += f.y;
            }
        }
        if (d16 < d) {                                 // clamped tail (<16 edges)
            int rr[8];
            #pragma unroll
            for (int jj = 0; jj < 8; ++jj) {
                int pos = d16 + 2 * jj + h;
                int v = slot2[s + pos];               // in-row, garbage past d
                rr[jj] = (pos < d) ? v : 0;
            }
            #pragma unroll
            for (int jj = 0; jj < 8; ++jj) {
                unsigned int v = g1h[rr[jj] * 32 + j];
                float2 f = __half22float2(*(__half2*)&v);
                bool ok = (d16 + 2 * jj + h) < d;     // uniform per half-wave
                acc0 += ok ? f.x : 0.f;
                acc1 += ok ? f.y : 0.f;
            }
        }
        acc0 += __shfl_xor(acc0, 32);                 // combine edge-halves
        acc1 += __shfl_xor(acc1, 32);
        if (h == 0) {
            unsigned int sv = g1h[node * 32 + j];
            float2 sf = __half22float2(*(__half2*)&sv);
            float dc = dinv[node];
            *(float2*)&aggh[n * 66 + 2 * j] =
                make_float2(dc * (acc0 + sf.x), dc * (acc1 + sf.y));
        }
    }
    // ---- overflow edges (expected ~200 total): exact, wave-local rows ----
    {
        int novf = min(ovf[0], OVF_CAP);
        int glo = g * NPG;
        for (int k = 0; k < novf; ++k) {
            int r = ovf[1 + 2 * k];
            int c = ovf[2 + 2 * k];
            int n = c - glo;
            if (n >= rbase && n < rbase + nn && h == 0) {
                unsigned int v = g1h[r * 32 + j];
                float2 f = __half22float2(*(__half2*)&v);
                float dc = dinv[c];
                aggh[n * 66 + 2 * j]     += dc * f.x;
                aggh[n * 66 + 2 * j + 1] += dc * f.y;
            }
        }
    }
    // no barrier: phase 2 reads only rows this wave wrote (same-wave lgkmcnt)

    // ---- phase 2: per-wave [nn][64] @ [64][128]; unconditional register blocks ----
    float2 b2v = *(const float2*)&b2[2 * lane];
    float pool0 = 0.f, pool1 = 0.f;
    if (wb < 4) {   // 13-row waves
        float acc0[13], acc1[13];
        #pragma unroll
        for (int i = 0; i < 13; ++i) { acc0[i] = 0.f; acc1[i] = 0.f; }
        float2 wv0 = *(const float2*)&W2[2 * lane];
        float2 wv1 = *(const float2*)&W2[128 + 2 * lane];
        for (int f = 0; f < 64; ++f) {
            float2 wnx = (f + 2 < 64) ? *(const float2*)&W2[(f + 2) * 128 + 2 * lane] : wv0;
            #pragma unroll
            for (int i = 0; i < 13; ++i) {
                float rv = aggh[(rbase + i) * 66 + f];   // LDS broadcast
                acc0[i] += rv * wv0.x;
                acc1[i] += rv * wv0.y;
            }
            wv0 = wv1; wv1 = wnx;
        }
        #pragma unroll
        for (int i = 0; i < 13; ++i) {
            pool0 += fmaxf(acc0[i] + b2v.x, 0.f);
            pool1 += fmaxf(acc1[i] + b2v.y, 0.f);
        }
    } else {        // 12-row waves
        float acc0[12], acc1[12];
        #pragma unroll
        for (int i = 0; i < 12; ++i) { acc0[i] = 0.f; acc1[i] = 0.f; }
        float2 wv0 = *(const float2*)&W2[2 * lane];
        float2 wv1 = *(const float2*)&W2[128 + 2 * lane];
        for (int f = 0; f < 64; ++f) {
            float2 wnx = (f + 2 < 64) ? *(const float2*)&W2[(f + 2) * 128 + 2 * lane] : wv0;
            #pragma unroll
            for (int i = 0; i < 12; ++i) {
                float rv = aggh[(rbase + i) * 66 + f];
                acc0[i] += rv * wv0.x;
                acc1[i] += rv * wv0.y;
            }
            wv0 = wv1; wv1 = wnx;
        }
        #pragma unroll
        for (int i = 0; i < 12; ++i) {
            pool0 += fmaxf(acc0[i] + b2v.x, 0.f);
            pool1 += fmaxf(acc1[i] + b2v.y, 0.f);
        }
    }

    pools[wb * 128 + 2 * lane]     = pool0;
    pools[wb * 128 + 2 * lane + 1] = pool1;
    __syncthreads();
    if (t < 128) {
        float z = 0.f;
        #pragma unroll
        for (int w = 0; w < 8; ++w) z += pools[w * 128 + t];
        zbuf[t] = z * (1.0f / NPG);
    }
    if (t < MDIM) zbuf[128 + t] = mv[g * MDIM + t];
    __syncthreads();
    if (t < 64) {
        float v = bc1[t];
        for (int k = 0; k < 160; ++k) v += zbuf[k] * Wc1[k * 64 + t];
        zz[t] = fmaxf(v, 0.f);
    }
    __syncthreads();
    if (t < NCDIM) {
        float o = bc2[t];
        #pragma unroll
        for (int k = 0; k < 64; ++k) o += zz[k] * Wc2[k * NCDIM + t];
        out[g * NCDIM + t] = o;
    }
}

extern "C" void kernel_launch(void* const* d_in, const int* in_sizes, int n_in,
                              void* d_out, int out_size, void* d_ws, size_t ws_size,
                              hipStream_t stream) {
    const float* x   = (const float*)d_in[0];
    const int*   ei  = (const int*)d_in[1];   // int64 in ref -> int32 on device
    const float* mv  = (const float*)d_in[3];
    const float* W1  = (const float*)d_in[4];
    const float* b1  = (const float*)d_in[5];
    const float* W2  = (const float*)d_in[6];
    const float* b2  = (const float*)d_in[7];
    const float* Wc1 = (const float*)d_in[8];
    const float* bc1 = (const float*)d_in[9];
    const float* Wc2 = (const float*)d_in[10];
    const float* bc2 = (const float*)d_in[11];
    float* out = (float*)d_out;
    float* ws  = (float*)d_ws;

    if (ws_size < (size_t)WS_FLOATS * sizeof(float)) return;  // proven available r12

    int*          slot2  = (int*)(ws + W_S2);
    int*          cnt    = (int*)(ws + W_CNT);
    float*        dinv   = ws + W_DINV;
    float4*       xd4    = (float4*)(ws + W_XD4);
    float4*       a4     = (float4*)(ws + W_A4);
    unsigned int* g1h    = (unsigned int*)(ws + W_G1H);
    int*          ovf    = (int*)(ws + W_OVF);

    hipMemsetAsync(cnt, 0, (size_t)NNODES * sizeof(int), stream);
    hipMemsetAsync(ovf, 0, sizeof(int), stream);

    k_fillbkt<<<FBLKS * NPART, 256, 0, stream>>>(ei, cnt, slot2, ovf);
    k_prep   <<<(NNODES + 255) / 256, 256, 0, stream>>>(cnt, x, dinv, xd4);
    k_ag1    <<<(NNODES + 255) / 256, 256, 0, stream>>>(cnt, slot2, xd4, a4,
                                                        W1, b1, (uint4*)g1h);
    k_ovfA   <<<1, 256, 0, stream>>>(ovf, xd4, dinv, (float*)a4);
    k_ovfG   <<<1, 256, 0, stream>>>(ovf, a4, W1, b1, g1h);
    k_fusedA <<<NGRAPH, 512, 0, stream>>>(cnt, slot2, ovf, g1h, dinv, mv,
                                          W2, b2, Wc1, bc1, Wc2, bc2, out);
}

// Round 22
// 342.625 us; speedup vs baseline: 1.1062x; 1.1062x over previous
//
#include <hip/hip_runtime.h>
#include <hip/hip_fp16.h>

#define NNODES 100000
#define NEDGES 3200000
#define NGRAPH 1000
#define NPG    100
#define MDIM   32
#define NCDIM  10

#define CAP     48         // bucket capacity; P(deg>48)~1.8e-3/node -> ~200 ovf edges
#define OVF_CAP 4096

#define NPART   8          // scatter partitions (== XCD count)
#define PSIZE   12500      // nodes per partition
#define FCHUNK  6250       // edges per chunk
#define FBLKS   (NEDGES / FCHUNK)   // 512 chunks

// ws layout (float units), total 36.0 MB (ws >= 40.4 MB proven in r12):
#define W_S2    0           // slot2: 100000*48 + 64 pad ints
#define W_CNT   4800064     // 100000 ints
#define W_DINV  4900064     // 100000 floats
#define W_XD4   5000064     // 100000 float4 (16B aligned)
#define W_A4    5400064     // 100000 float4
#define W_G1H   5800064     // 3200000 uints ([node][32] half2)
#define W_OVF   9000064     // 1 + 2*4096 ints
#define WS_FLOATS 9008257   // 36.0 MB

// ---------------- K1: bucket fill, XCD-partitioned; builds cnt on the fly ---------
__global__ __launch_bounds__(256) void k_fillbkt(const int* __restrict__ ei,
                                                 int* __restrict__ cnt,
                                                 int* __restrict__ slot2,
                                                 int* __restrict__ ovf) {
    int part  = blockIdx.x & (NPART - 1);
    int chunk = blockIdx.x >> 3;
    int base  = chunk * FCHUNK;
    int end   = base + FCHUNK;
    int clo   = part * PSIZE;
    int chi   = clo + PSIZE;
    for (int e = base + threadIdx.x; e < end; e += 256) {
        int c = ei[NEDGES + e];
        if (c >= clo && c < chi) {
            int r = ei[e];
            int idx = atomicAdd(&cnt[c], 1);
            if (idx < CAP) {
                slot2[c * CAP + idx] = r;
            } else {
                int o = atomicAdd(&ovf[0], 1);
                if (o < OVF_CAP) { ovf[1 + 2 * o] = r; ovf[2 + 2 * o] = c; }
            }
        }
    }
}

// ---------------- K2: dinv + packed xd4 from final cnt ----------------
__global__ __launch_bounds__(256) void k_prep(const int* __restrict__ cnt,
                                              const float* __restrict__ x,
                                              float* __restrict__ dinv,
                                              float4* __restrict__ xd4) {
    int i = blockIdx.x * blockDim.x + threadIdx.x;
    if (i >= NNODES) return;
    float di = rsqrtf((float)cnt[i] + 1.0f);
    dinv[i] = di;
    xd4[i] = make_float4(x[3 * i], x[3 * i + 1], x[3 * i + 2], di);
}

// ---------------- K3: a4[i] from bucket; mask-free main + clamped tail -----------
__global__ void k_a(const int* __restrict__ cnt, const int* __restrict__ slot2,
                    const float4* __restrict__ xd4, float4* __restrict__ a4) {
    int i = blockIdx.x * blockDim.x + threadIdx.x;
    if (i >= NNODES) return;
    int d = min(cnt[i], CAP);
    int s = i * CAP;
    int d8 = d & ~7;
    float ax = 0.f, ay = 0.f, az = 0.f;
    for (int k = 0; k < d8; k += 8) {            // mask-free main
        float4 xr[8];
        #pragma unroll
        for (int j = 0; j < 8; ++j) xr[j] = xd4[slot2[s + k + j]];
        #pragma unroll
        for (int j = 0; j < 8; ++j) {
            ax += xr[j].w * xr[j].x; ay += xr[j].w * xr[j].y; az += xr[j].w * xr[j].z;
        }
    }
    if (d8 < d) {                                // clamped tail (<8 edges)
        float4 xr[8];
        #pragma unroll
        for (int j = 0; j < 8; ++j) {
            int idx = slot2[s + d8 + j];         // in-row, may be garbage past d
            xr[j] = xd4[(d8 + j < d) ? idx : 0];
        }
        #pragma unroll
        for (int j = 0; j < 8; ++j) {
            float u = (d8 + j < d) ? xr[j].w : 0.f;
            ax += u * xr[j].x; ay += u * xr[j].y; az += u * xr[j].z;
        }
    }
    float4 xi = xd4[i];
    float di = xi.w;
    a4[i] = make_float4(di * (ax + di * xi.x),
                        di * (ay + di * xi.y),
                        di * (az + di * xi.z), di);
}

// ---------------- K3b: exact fixup of a4 for overflow edges (tiny) ----------------
__global__ void k_ovfA(const int* __restrict__ ovf, const float4* __restrict__ xd4,
                       const float* __restrict__ dinv, float* __restrict__ a4f) {
    int n = min(ovf[0], OVF_CAP);
    for (int k = threadIdx.x; k < n; k += 256) {
        int r = ovf[1 + 2 * k];
        int c = ovf[2 + 2 * k];
        float4 xr = xd4[r];
        float s = dinv[c] * xr.w;
        atomicAdd(&a4f[c * 4 + 0], s * xr.x);
        atomicAdd(&a4f[c * 4 + 1], s * xr.y);
        atomicAdd(&a4f[c * 4 + 2], s * xr.z);
    }
}

// ---------------- K4: g1h[i][2j:2j+1] = fp16( dinv_i * relu(a_i.W1col + b1) ) -----
__global__ __launch_bounds__(256) void k_g1(const float4* __restrict__ a4,
                                            const float* __restrict__ W1,
                                            const float* __restrict__ b1,
                                            unsigned int* __restrict__ g1h) {
    int t = blockIdx.x * blockDim.x + threadIdx.x;   // t = i*32 + j
    int i = t >> 5, j = t & 31;
    if (i >= NNODES) return;
    float4 ai = a4[i];
    int f0 = 2 * j, f1 = f0 + 1;
    float h0 = fmaxf(ai.x * W1[f0] + ai.y * W1[64 + f0] + ai.z * W1[128 + f0] + b1[f0], 0.f);
    float h1 = fmaxf(ai.x * W1[f1] + ai.y * W1[64 + f1] + ai.z * W1[128 + f1] + b1[f1], 0.f);
    __half2 hv = __floats2half2_rn(ai.w * h0, ai.w * h1);
    g1h[t] = *(unsigned int*)&hv;
}

// ---------------- K5: per-graph, 8 waves (512 thr); r18 structure -----------------
__global__ __launch_bounds__(512, 8) void k_fusedA(
    const int* __restrict__ cnt, const int* __restrict__ slot2,
    const int* __restrict__ ovf,
    const unsigned int* __restrict__ g1h, const float* __restrict__ dinv,
    const float* __restrict__ mv,
    const float* __restrict__ W2, const float* __restrict__ b2,
    const float* __restrict__ Wc1, const float* __restrict__ bc1,
    const float* __restrict__ Wc2, const float* __restrict__ bc2,
    float* __restrict__ out)
{
    __shared__ float aggh[NPG * 66];   // 26.4 KB, even pad -> aligned float2 rows
    __shared__ float pools[8 * 128];   // 4 KB
    __shared__ float zbuf[160];
    __shared__ float zz[64];

    int g = blockIdx.x;
    int t = threadIdx.x;
    int wb = t >> 6;           // wave 0..7
    int lane = t & 63;
    int h = lane >> 5;         // which edge of the pair this half-wave handles
    int j = lane & 31;         // feature-pair index (features 2j, 2j+1)
    // waves 0-3 own 13 contiguous rows, waves 4-7 own 12:  4*13 + 4*12 = 100
    int nn    = (wb < 4) ? 13 : 12;
    int rbase = (wb < 4) ? wb * 13 : 52 + (wb - 4) * 12;

    // ---- phase 1: per-node aggregation; 256B wave-load covers TWO edges ----
    for (int i = 0; i < nn; ++i) {
        int n = rbase + i;
        int node = g * NPG + n;
        int s = node * CAP;
        int d = min(cnt[node], CAP);
        int d16 = d & ~15;
        float acc0 = 0.f, acc1 = 0.f;
        for (int k0 = 0; k0 < d16; k0 += 16) {        // mask-free main loop
            int rr[8];
            #pragma unroll
            for (int jj = 0; jj < 8; ++jj)
                rr[jj] = slot2[s + k0 + 2 * jj + h];  // all positions valid
            unsigned int pre[8];
            #pragma unroll
            for (int jj = 0; jj < 8; ++jj)
                pre[jj] = g1h[rr[jj] * 32 + j];       // coalesced 256B/wave
            #pragma unroll
            for (int jj = 0; jj < 8; ++jj) {
                float2 f = __half22float2(*(__half2*)&pre[jj]);
                acc0 += f.x;
                acc1 += f.y;
            }
        }
        if (d16 < d) {                                 // clamped tail (<16 edges)
            int rr[8];
            #pragma unroll
            for (int jj = 0; jj < 8; ++jj) {
                int pos = d16 + 2 * jj + h;
                int v = slot2[s + pos];               // in-row, garbage past d
                rr[jj] = (pos < d) ? v : 0;
            }
            #pragma unroll
            for (int jj = 0; jj < 8; ++jj) {
                unsigned int v = g1h[rr[jj] * 32 + j];
                float2 f = __half22float2(*(__half2*)&v);
                bool ok = (d16 + 2 * jj + h) < d;     // uniform per half-wave
                acc0 += ok ? f.x : 0.f;
                acc1 += ok ? f.y : 0.f;
            }
        }
        acc0 += __shfl_xor(acc0, 32);                 // combine edge-halves
        acc1 += __shfl_xor(acc1, 32);
        if (h == 0) {
            unsigned int sv = g1h[node * 32 + j];
            float2 sf = __half22float2(*(__half2*)&sv);
            float dc = dinv[node];
            *(float2*)&aggh[n * 66 + 2 * j] =
                make_float2(dc * (acc0 + sf.x), dc * (acc1 + sf.y));
        }
    }
    // ---- overflow edges (expected ~200 total): exact, wave-local rows ----
    {
        int novf = min(ovf[0], OVF_CAP);
        int glo = g * NPG;
        for (int k = 0; k < novf; ++k) {
            int r = ovf[1 + 2 * k];
            int c = ovf[2 + 2 * k];
            int n = c - glo;
            if (n >= rbase && n < rbase + nn && h == 0) {
                unsigned int v = g1h[r * 32 + j];
                float2 f = __half22float2(*(__half2*)&v);
                float dc = dinv[c];
                aggh[n * 66 + 2 * j]     += dc * f.x;
                aggh[n * 66 + 2 * j + 1] += dc * f.y;
            }
        }
    }
    // no barrier: phase 2 reads only rows this wave wrote (same-wave lgkmcnt)

    // ---- phase 2: per-wave [nn][64] @ [64][128]; unconditional register blocks ----
    float2 b2v = *(const float2*)&b2[2 * lane];
    float pool0 = 0.f, pool1 = 0.f;
    if (wb < 4) {   // 13-row waves
        float acc0[13], acc1[13];
        #pragma unroll
        for (int i = 0; i < 13; ++i) { acc0[i] = 0.f; acc1[i] = 0.f; }
        float2 wv0 = *(const float2*)&W2[2 * lane];
        float2 wv1 = *(const float2*)&W2[128 + 2 * lane];
        for (int f = 0; f < 64; ++f) {
            float2 wnx = (f + 2 < 64) ? *(const float2*)&W2[(f + 2) * 128 + 2 * lane] : wv0;
            #pragma unroll
            for (int i = 0; i < 13; ++i) {
                float rv = aggh[(rbase + i) * 66 + f];   // LDS broadcast
                acc0[i] += rv * wv0.x;
                acc1[i] += rv * wv0.y;
            }
            wv0 = wv1; wv1 = wnx;
        }
        #pragma unroll
        for (int i = 0; i < 13; ++i) {
            pool0 += fmaxf(acc0[i] + b2v.x, 0.f);
            pool1 += fmaxf(acc1[i] + b2v.y, 0.f);
        }
    } else {        // 12-row waves
        float acc0[12], acc1[12];
        #pragma unroll
        for (int i = 0; i < 12; ++i) { acc0[i] = 0.f; acc1[i] = 0.f; }
        float2 wv0 = *(const float2*)&W2[2 * lane];
        float2 wv1 = *(const float2*)&W2[128 + 2 * lane];
        for (int f = 0; f < 64; ++f) {
            float2 wnx = (f + 2 < 64) ? *(const float2*)&W2[(f + 2) * 128 + 2 * lane] : wv0;
            #pragma unroll
            for (int i = 0; i < 12; ++i) {
                float rv = aggh[(rbase + i) * 66 + f];
                acc0[i] += rv * wv0.x;
                acc1[i] += rv * wv0.y;
            }
            wv0 = wv1; wv1 = wnx;
        }
        #pragma unroll
        for (int i = 0; i < 12; ++i) {
            pool0 += fmaxf(acc0[i] + b2v.x, 0.f);
            pool1 += fmaxf(acc1[i] + b2v.y, 0.f);
        }
    }

    pools[wb * 128 + 2 * lane]     = pool0;
    pools[wb * 128 + 2 * lane + 1] = pool1;
    __syncthreads();
    if (t < 128) {
        float z = 0.f;
        #pragma unroll
        for (int w = 0; w < 8; ++w) z += pools[w * 128 + t];
        zbuf[t] = z * (1.0f / NPG);
    }
    if (t < MDIM) zbuf[128 + t] = mv[g * MDIM + t];
    __syncthreads();
    if (t < 64) {
        float v = bc1[t];
        for (int k = 0; k < 160; ++k) v += zbuf[k] * Wc1[k * 64 + t];
        zz[t] = fmaxf(v, 0.f);
    }
    __syncthreads();
    if (t < NCDIM) {
        float o = bc2[t];
        #pragma unroll
        for (int k = 0; k < 64; ++k) o += zz[k] * Wc2[k * NCDIM + t];
        out[g * NCDIM + t] = o;
    }
}

extern "C" void kernel_launch(void* const* d_in, const int* in_sizes, int n_in,
                              void* d_out, int out_size, void* d_ws, size_t ws_size,
                              hipStream_t stream) {
    const float* x   = (const float*)d_in[0];
    const int*   ei  = (const int*)d_in[1];   // int64 in ref -> int32 on device
    const float* mv  = (const float*)d_in[3];
    const float* W1  = (const float*)d_in[4];
    const float* b1  = (const float*)d_in[5];
    const float* W2  = (const float*)d_in[6];
    const float* b2  = (const float*)d_in[7];
    const float* Wc1 = (const float*)d_in[8];
    const float* bc1 = (const float*)d_in[9];
    const float* Wc2 = (const float*)d_in[10];
    const float* bc2 = (const float*)d_in[11];
    float* out = (float*)d_out;
    float* ws  = (float*)d_ws;

    if (ws_size < (size_t)WS_FLOATS * sizeof(float)) return;  // proven available r12

    int*          slot2  = (int*)(ws + W_S2);
    int*          cnt    = (int*)(ws + W_CNT);
    float*        dinv   = ws + W_DINV;
    float4*       xd4    = (float4*)(ws + W_XD4);
    float4*       a4     = (float4*)(ws + W_A4);
    unsigned int* g1h    = (unsigned int*)(ws + W_G1H);
    int*          ovf    = (int*)(ws + W_OVF);

    hipMemsetAsync(cnt, 0, (size_t)NNODES * sizeof(int), stream);
    hipMemsetAsync(ovf, 0, sizeof(int), stream);

    k_fillbkt<<<FBLKS * NPART, 256, 0, stream>>>(ei, cnt, slot2, ovf);
    k_prep   <<<(NNODES + 255) / 256, 256, 0, stream>>>(cnt, x, dinv, xd4);
    k_a      <<<(NNODES + 255) / 256, 256, 0, stream>>>(cnt, slot2, xd4, a4);
    k_ovfA   <<<1, 256, 0, stream>>>(ovf, xd4, dinv, (float*)a4);
    k_g1     <<<(NNODES * 32) / 256, 256, 0, stream>>>(a4, W1, b1, g1h);
    k_fusedA <<<NGRAPH, 512, 0, stream>>>(cnt, slot2, ovf, g1h, dinv, mv,
                                          W2, b2, Wc1, bc1, Wc2, bc2, out);
}

// Round 23
// 334.915 us; speedup vs baseline: 1.1317x; 1.0230x over previous
//
#include <hip/hip_runtime.h>
#include <hip/hip_fp16.h>

#define NNODES 100000
#define NEDGES 3200000
#define NGRAPH 1000
#define NPG    100
#define MDIM   32
#define NCDIM  10

#define CAP     48         // bucket capacity; P(deg>48)~1.8e-3/node -> ~200 ovf edges
#define OVF_CAP 4096

#define NPART   8          // scatter partitions (== XCD count)
#define PSIZE   12500      // nodes per partition
#define FCHUNK  6250       // edges per chunk
#define FBLKS   (NEDGES / FCHUNK)   // 512 chunks

// ws layout (float units), total 36.0 MB (ws >= 40.4 MB proven in r12):
#define W_S2    0           // slot2: 100000*48 + 64 pad ints
#define W_CNT   4800064     // 100000 ints
#define W_DINV  4900064     // 100000 floats
#define W_XD4   5000064     // 100000 float4 (16B aligned)
#define W_A4    5400064     // 100000 float4
#define W_G1H   5800064     // 3200000 uints ([node][32] half2)
#define W_OVF   9000064     // 1 + 2*4096 ints
#define WS_FLOATS 9008257   // 36.0 MB

// ---------------- K1: bucket fill, XCD-partitioned; builds cnt on the fly ---------
__global__ __launch_bounds__(256) void k_fillbkt(const int* __restrict__ ei,
                                                 int* __restrict__ cnt,
                                                 int* __restrict__ slot2,
                                                 int* __restrict__ ovf) {
    int part  = blockIdx.x & (NPART - 1);
    int chunk = blockIdx.x >> 3;
    int base  = chunk * FCHUNK;
    int end   = base + FCHUNK;
    int clo   = part * PSIZE;
    int chi   = clo + PSIZE;
    for (int e = base + threadIdx.x; e < end; e += 256) {
        int c = ei[NEDGES + e];
        if (c >= clo && c < chi) {
            int r = ei[e];
            int idx = atomicAdd(&cnt[c], 1);
            if (idx < CAP) {
                slot2[c * CAP + idx] = r;
            } else {
                int o = atomicAdd(&ovf[0], 1);
                if (o < OVF_CAP) { ovf[1 + 2 * o] = r; ovf[2 + 2 * o] = c; }
            }
        }
    }
}

// ---------------- K2: dinv + packed xd4 from final cnt ----------------
__global__ __launch_bounds__(256) void k_prep(const int* __restrict__ cnt,
                                              const float* __restrict__ x,
                                              float* __restrict__ dinv,
                                              float4* __restrict__ xd4) {
    int i = blockIdx.x * blockDim.x + threadIdx.x;
    if (i >= NNODES) return;
    float di = rsqrtf((float)cnt[i] + 1.0f);
    dinv[i] = di;
    xd4[i] = make_float4(x[3 * i], x[3 * i + 1], x[3 * i + 2], di);
}

// ---------------- K3: a4[i] from bucket; mask-free main + clamped tail -----------
__global__ void k_a(const int* __restrict__ cnt, const int* __restrict__ slot2,
                    const float4* __restrict__ xd4, float4* __restrict__ a4) {
    int i = blockIdx.x * blockDim.x + threadIdx.x;
    if (i >= NNODES) return;
    int d = min(cnt[i], CAP);
    int s = i * CAP;
    int d8 = d & ~7;
    float ax = 0.f, ay = 0.f, az = 0.f;
    for (int k = 0; k < d8; k += 8) {            // mask-free main
        float4 xr[8];
        #pragma unroll
        for (int j = 0; j < 8; ++j) xr[j] = xd4[slot2[s + k + j]];
        #pragma unroll
        for (int j = 0; j < 8; ++j) {
            ax += xr[j].w * xr[j].x; ay += xr[j].w * xr[j].y; az += xr[j].w * xr[j].z;
        }
    }
    if (d8 < d) {                                // clamped tail (<8 edges)
        float4 xr[8];
        #pragma unroll
        for (int j = 0; j < 8; ++j) {
            int idx = slot2[s + d8 + j];         // in-row, may be garbage past d
            xr[j] = xd4[(d8 + j < d) ? idx : 0];
        }
        #pragma unroll
        for (int j = 0; j < 8; ++j) {
            float u = (d8 + j < d) ? xr[j].w : 0.f;
            ax += u * xr[j].x; ay += u * xr[j].y; az += u * xr[j].z;
        }
    }
    float4 xi = xd4[i];
    float di = xi.w;
    a4[i] = make_float4(di * (ax + di * xi.x),
                        di * (ay + di * xi.y),
                        di * (az + di * xi.z), di);
}

// ---------------- K3b: exact fixup of a4 for overflow edges (tiny) ----------------
__global__ void k_ovfA(const int* __restrict__ ovf, const float4* __restrict__ xd4,
                       const float* __restrict__ dinv, float* __restrict__ a4f) {
    int n = min(ovf[0], OVF_CAP);
    for (int k = threadIdx.x; k < n; k += 256) {
        int r = ovf[1 + 2 * k];
        int c = ovf[2 + 2 * k];
        float4 xr = xd4[r];
        float s = dinv[c] * xr.w;
        atomicAdd(&a4f[c * 4 + 0], s * xr.x);
        atomicAdd(&a4f[c * 4 + 1], s * xr.y);
        atomicAdd(&a4f[c * 4 + 2], s * xr.z);
    }
}

// ---------------- K4: g1h[i][2j:2j+1] = fp16( dinv_i * relu(a_i.W1col + b1) ) -----
__global__ __launch_bounds__(256) void k_g1(const float4* __restrict__ a4,
                                            const float* __restrict__ W1,
                                            const float* __restrict__ b1,
                                            unsigned int* __restrict__ g1h) {
    int t = blockIdx.x * blockDim.x + threadIdx.x;   // t = i*32 + j
    int i = t >> 5, j = t & 31;
    if (i >= NNODES) return;
    float4 ai = a4[i];
    int f0 = 2 * j, f1 = f0 + 1;
    float h0 = fmaxf(ai.x * W1[f0] + ai.y * W1[64 + f0] + ai.z * W1[128 + f0] + b1[f0], 0.f);
    float h1 = fmaxf(ai.x * W1[f1] + ai.y * W1[64 + f1] + ai.z * W1[128 + f1] + b1[f1], 0.f);
    __half2 hv = __floats2half2_rn(ai.w * h0, ai.w * h1);
    g1h[t] = *(unsigned int*)&hv;
}

// ---------------- K5: per-graph, 8 waves; slot-prefetch pipelined phase 1 ---------
__global__ __launch_bounds__(512, 8) void k_fusedA(
    const int* __restrict__ cnt, const int* __restrict__ slot2,
    const int* __restrict__ ovf,
    const unsigned int* __restrict__ g1h, const float* __restrict__ dinv,
    const float* __restrict__ mv,
    const float* __restrict__ W2, const float* __restrict__ b2,
    const float* __restrict__ Wc1, const float* __restrict__ bc1,
    const float* __restrict__ Wc2, const float* __restrict__ bc2,
    float* __restrict__ out)
{
    __shared__ float aggh[NPG * 66];   // 26.4 KB, even pad -> aligned float2 rows
    __shared__ float pools[8 * 128];   // 4 KB
    __shared__ float zbuf[160];
    __shared__ float zz[64];

    int g = blockIdx.x;
    int t = threadIdx.x;
    int wb = t >> 6;           // wave 0..7
    int lane = t & 63;
    int h = lane >> 5;         // which edge of the pair this half-wave handles
    int j = lane & 31;         // feature-pair index (features 2j, 2j+1)
    // waves 0-3 own 13 contiguous rows, waves 4-7 own 12:  4*13 + 4*12 = 100
    int nn    = (wb < 4) ? 13 : 12;
    int rbase = (wb < 4) ? wb * 13 : 52 + (wb - 4) * 12;

    // ---- phase 1: per-node aggregation; slot reads prefetched 1 iter ahead ----
    for (int i = 0; i < nn; ++i) {
        int n = rbase + i;
        int node = g * NPG + n;
        int s = node * CAP;
        int d = min(cnt[node], CAP);
        int d16 = d & ~15;
        // hoisted: self-row + dinv issued early, consumed after edge loop
        unsigned int sv = g1h[node * 32 + j];
        float dc = dinv[node];
        float acc0 = 0.f, acc1 = 0.f;
        int rr[8];
        #pragma unroll
        for (int jj = 0; jj < 8; ++jj)
            rr[jj] = slot2[s + 2 * jj + h];               // batch 0 (in-row, pad-safe)
        for (int k0 = 0; k0 < d16; k0 += 16) {            // mask-free main loop
            unsigned int pre[8];
            #pragma unroll
            for (int jj = 0; jj < 8; ++jj)
                pre[jj] = g1h[rr[jj] * 32 + j];           // coalesced 256B/wave
            int rrn[8];
            #pragma unroll
            for (int jj = 0; jj < 8; ++jj)                // prefetch next batch
                rrn[jj] = slot2[s + k0 + 16 + 2 * jj + h];// <= s+63: 64-int pad safe
            #pragma unroll
            for (int jj = 0; jj < 8; ++jj) {
                float2 f = __half22float2(*(__half2*)&pre[jj]);
                acc0 += f.x;
                acc1 += f.y;
            }
            #pragma unroll
            for (int jj = 0; jj < 8; ++jj) rr[jj] = rrn[jj];
        }
        if (d16 < d) {                                 // clamped tail (<16 edges)
            // rr already holds batch at k0=d16 (prefetched or batch 0)
            int rrt[8];
            #pragma unroll
            for (int jj = 0; jj < 8; ++jj) {
                int pos = d16 + 2 * jj + h;
                rrt[jj] = (pos < d) ? rr[jj] : 0;
            }
            #pragma unroll
            for (int jj = 0; jj < 8; ++jj) {
                unsigned int v = g1h[rrt[jj] * 32 + j];
                float2 f = __half22float2(*(__half2*)&v);
                bool ok = (d16 + 2 * jj + h) < d;     // uniform per half-wave
                acc0 += ok ? f.x : 0.f;
                acc1 += ok ? f.y : 0.f;
            }
        }
        acc0 += __shfl_xor(acc0, 32);                 // combine edge-halves
        acc1 += __shfl_xor(acc1, 32);
        if (h == 0) {
            float2 sf = __half22float2(*(__half2*)&sv);
            *(float2*)&aggh[n * 66 + 2 * j] =
                make_float2(dc * (acc0 + sf.x), dc * (acc1 + sf.y));
        }
    }
    // ---- overflow edges (expected ~200 total): exact, wave-local rows ----
    {
        int novf = min(ovf[0], OVF_CAP);
        int glo = g * NPG;
        for (int k = 0; k < novf; ++k) {
            int r = ovf[1 + 2 * k];
            int c = ovf[2 + 2 * k];
            int n = c - glo;
            if (n >= rbase && n < rbase + nn && h == 0) {
                unsigned int v = g1h[r * 32 + j];
                float2 f = __half22float2(*(__half2*)&v);
                float dc = dinv[c];
                aggh[n * 66 + 2 * j]     += dc * f.x;
                aggh[n * 66 + 2 * j + 1] += dc * f.y;
            }
        }
    }
    // no barrier: phase 2 reads only rows this wave wrote (same-wave lgkmcnt)

    // ---- phase 2: per-wave [nn][64] @ [64][128]; unconditional register blocks ----
    float2 b2v = *(const float2*)&b2[2 * lane];
    float pool0 = 0.f, pool1 = 0.f;
    if (wb < 4) {   // 13-row waves
        float acc0[13], acc1[13];
        #pragma unroll
        for (int i = 0; i < 13; ++i) { acc0[i] = 0.f; acc1[i] = 0.f; }
        float2 wv0 = *(const float2*)&W2[2 * lane];
        float2 wv1 = *(const float2*)&W2[128 + 2 * lane];
        for (int f = 0; f < 64; ++f) {
            float2 wnx = (f + 2 < 64) ? *(const float2*)&W2[(f + 2) * 128 + 2 * lane] : wv0;
            #pragma unroll
            for (int i = 0; i < 13; ++i) {
                float rv = aggh[(rbase + i) * 66 + f];   // LDS broadcast
                acc0[i] += rv * wv0.x;
                acc1[i] += rv * wv0.y;
            }
            wv0 = wv1; wv1 = wnx;
        }
        #pragma unroll
        for (int i = 0; i < 13; ++i) {
            pool0 += fmaxf(acc0[i] + b2v.x, 0.f);
            pool1 += fmaxf(acc1[i] + b2v.y, 0.f);
        }
    } else {        // 12-row waves
        float acc0[12], acc1[12];
        #pragma unroll
        for (int i = 0; i < 12; ++i) { acc0[i] = 0.f; acc1[i] = 0.f; }
        float2 wv0 = *(const float2*)&W2[2 * lane];
        float2 wv1 = *(const float2*)&W2[128 + 2 * lane];
        for (int f = 0; f < 64; ++f) {
            float2 wnx = (f + 2 < 64) ? *(const float2*)&W2[(f + 2) * 128 + 2 * lane] : wv0;
            #pragma unroll
            for (int i = 0; i < 12; ++i) {
                float rv = aggh[(rbase + i) * 66 + f];
                acc0[i] += rv * wv0.x;
                acc1[i] += rv * wv0.y;
            }
            wv0 = wv1; wv1 = wnx;
        }
        #pragma unroll
        for (int i = 0; i < 12; ++i) {
            pool0 += fmaxf(acc0[i] + b2v.x, 0.f);
            pool1 += fmaxf(acc1[i] + b2v.y, 0.f);
        }
    }

    pools[wb * 128 + 2 * lane]     = pool0;
    pools[wb * 128 + 2 * lane + 1] = pool1;
    __syncthreads();
    if (t < 128) {
        float z = 0.f;
        #pragma unroll
        for (int w = 0; w < 8; ++w) z += pools[w * 128 + t];
        zbuf[t] = z * (1.0f / NPG);
    }
    if (t < MDIM) zbuf[128 + t] = mv[g * MDIM + t];
    __syncthreads();
    if (t < 64) {
        float v = bc1[t];
        for (int k = 0; k < 160; ++k) v += zbuf[k] * Wc1[k * 64 + t];
        zz[t] = fmaxf(v, 0.f);
    }
    __syncthreads();
    if (t < NCDIM) {
        float o = bc2[t];
        #pragma unroll
        for (int k = 0; k < 64; ++k) o += zz[k] * Wc2[k * NCDIM + t];
        out[g * NCDIM + t] = o;
    }
}

extern "C" void kernel_launch(void* const* d_in, const int* in_sizes, int n_in,
                              void* d_out, int out_size, void* d_ws, size_t ws_size,
                              hipStream_t stream) {
    const float* x   = (const float*)d_in[0];
    const int*   ei  = (const int*)d_in[1];   // int64 in ref -> int32 on device
    const float* mv  = (const float*)d_in[3];
    const float* W1  = (const float*)d_in[4];
    const float* b1  = (const float*)d_in[5];
    const float* W2  = (const float*)d_in[6];
    const float* b2  = (const float*)d_in[7];
    const float* Wc1 = (const float*)d_in[8];
    const float* bc1 = (const float*)d_in[9];
    const float* Wc2 = (const float*)d_in[10];
    const float* bc2 = (const float*)d_in[11];
    float* out = (float*)d_out;
    float* ws  = (float*)d_ws;

    if (ws_size < (size_t)WS_FLOATS * sizeof(float)) return;  // proven available r12

    int*          slot2  = (int*)(ws + W_S2);
    int*          cnt    = (int*)(ws + W_CNT);
    float*        dinv   = ws + W_DINV;
    float4*       xd4    = (float4*)(ws + W_XD4);
    float4*       a4     = (float4*)(ws + W_A4);
    unsigned int* g1h    = (unsigned int*)(ws + W_G1H);
    int*          ovf    = (int*)(ws + W_OVF);

    hipMemsetAsync(cnt, 0, (size_t)NNODES * sizeof(int), stream);
    hipMemsetAsync(ovf, 0, sizeof(int), stream);

    k_fillbkt<<<FBLKS * NPART, 256, 0, stream>>>(ei, cnt, slot2, ovf);
    k_prep   <<<(NNODES + 255) / 256, 256, 0, stream>>>(cnt, x, dinv, xd4);
    k_a      <<<(NNODES + 255) / 256, 256, 0, stream>>>(cnt, slot2, xd4, a4);
    k_ovfA   <<<1, 256, 0, stream>>>(ovf, xd4, dinv, (float*)a4);
    k_g1     <<<(NNODES * 32) / 256, 256, 0, stream>>>(a4, W1, b1, g1h);
    k_fusedA <<<NGRAPH, 512, 0, stream>>>(cnt, slot2, ovf, g1h, dinv, mv,
                                          W2, b2, Wc1, bc1, Wc2, bc2, out);
}